// Round 6
// baseline (199.029 us; speedup 1.0000x reference)
//
#include <hip/hip_runtime.h>
#include <math.h>

#define D_MODEL 512
#define NH      8
#define DK      128
#define HALFD   64
#define NKEYS   256
#define TOPK    8
#define NTOK    2048

// ---------------- Kernel A: q = x @ Wq + bq  (fp32 tiled GEMM) ----------------
// M=2048, N=1024, K=512.  BM=BN=64, BK=16, 256 threads, 4x4 per thread. 512 blocks = 2/CU.
__global__ __launch_bounds__(256) void qproj_gemm(const float* __restrict__ A,
                                                  const float* __restrict__ B,
                                                  const float* __restrict__ bias,
                                                  float* __restrict__ C) {
  const int N = NH * DK, K = D_MODEL;
  __shared__ float As[16][68];
  __shared__ float Bs[16][68];
  int tid = threadIdx.x;
  int tx = tid & 15, ty = tid >> 4;
  int m0 = blockIdx.y * 64, n0 = blockIdx.x * 64;
  float c[4][4];
#pragma unroll
  for (int i = 0; i < 4; ++i)
#pragma unroll
    for (int j = 0; j < 4; ++j) c[i][j] = 0.f;

  for (int k0 = 0; k0 < K; k0 += 16) {
    {
      int row = tid >> 2, kk = (tid & 3) << 2;
      float4 av = *(const float4*)(A + (size_t)(m0 + row) * K + k0 + kk);
      As[kk + 0][row] = av.x;
      As[kk + 1][row] = av.y;
      As[kk + 2][row] = av.z;
      As[kk + 3][row] = av.w;
    }
    {
      int kr = tid >> 4, nn = (tid & 15) << 2;
      *(float4*)&Bs[kr][nn] = *(const float4*)(B + (size_t)(k0 + kr) * N + n0 + nn);
    }
    __syncthreads();
#pragma unroll
    for (int k = 0; k < 16; ++k) {
      float4 a = *(const float4*)&As[k][ty << 2];
      float4 b = *(const float4*)&Bs[k][tx << 2];
      float av[4] = {a.x, a.y, a.z, a.w};
      float bv[4] = {b.x, b.y, b.z, b.w};
#pragma unroll
      for (int i = 0; i < 4; ++i)
#pragma unroll
        for (int j = 0; j < 4; ++j) c[i][j] += av[i] * bv[j];
    }
    __syncthreads();
  }
#pragma unroll
  for (int i = 0; i < 4; ++i) {
    int m = m0 + (ty << 2) + i;
#pragma unroll
    for (int j = 0; j < 4; ++j) {
      int n = n0 + (tx << 2) + j;
      C[(size_t)m * N + n] = c[i][j] + bias[n];
    }
  }
}

// ---------------- Kernel B: fused scores + two-stage top-k + softmax ----------------
// One block per (16-token tile, head). Scores live only in LDS (no 67 MB round-trip).
#define CE(a, b)                                                        \
  do {                                                                  \
    if (lv[a] < lv[b] || (lv[a] == lv[b] && li[a] > li[b])) {           \
      float tv_ = lv[a]; lv[a] = lv[b]; lv[b] = tv_;                    \
      int ti_ = li[a]; li[a] = li[b]; li[b] = ti_;                      \
    }                                                                   \
  } while (0)

__global__ __launch_bounds__(256) void score_topk_fused(const float* __restrict__ qbuf,
                                                        const float* __restrict__ keys,
                                                        int* __restrict__ widx,
                                                        float* __restrict__ wval) {
  int h = blockIdx.y;
  int b0 = blockIdx.x * 16;
  int tid = threadIdx.x;

  __shared__ float q_lds[16][DK];        // 8 KB
  __shared__ float sc[2][16][NKEYS];     // 32 KB

  // stage q: 16 tokens x 128 dims, coalesced
  for (int i = tid; i < 16 * 32; i += 256) {
    int t = i >> 5, c4 = i & 31;
    *(float4*)&q_lds[t][c4 * 4] =
        *(const float4*)(qbuf + (size_t)(b0 + t) * (NH * DK) + h * DK + c4 * 4);
  }
  __syncthreads();

  // compute phase: thread = (token-group tg = tid>>6, n-group ng = tid&63)
  // handles 4 tokens x 4 n per s; keys L2-resident.
  {
    int tg = tid >> 6, ng = tid & 63;
#pragma unroll
    for (int s = 0; s < 2; ++s) {
      const float* kbase = keys + (size_t)(h * 2 + s) * NKEYS * HALFD;
      float acc[4][4];
#pragma unroll
      for (int t = 0; t < 4; ++t)
#pragma unroll
        for (int n = 0; n < 4; ++n) acc[t][n] = 0.f;
      for (int c4 = 0; c4 < 16; ++c4) {
        float4 kv[4];
#pragma unroll
        for (int n = 0; n < 4; ++n)
          kv[n] = *(const float4*)(kbase + (size_t)(ng * 4 + n) * HALFD + c4 * 4);
        float4 qv[4];
#pragma unroll
        for (int t = 0; t < 4; ++t)
          qv[t] = *(const float4*)&q_lds[tg * 4 + t][s * HALFD + c4 * 4];
#pragma unroll
        for (int t = 0; t < 4; ++t)
#pragma unroll
          for (int n = 0; n < 4; ++n) {
            acc[t][n] += qv[t].x * kv[n].x + qv[t].y * kv[n].y +
                         qv[t].z * kv[n].z + qv[t].w * kv[n].w;
          }
      }
#pragma unroll
      for (int t = 0; t < 4; ++t) {
        float4 w = make_float4(acc[t][0], acc[t][1], acc[t][2], acc[t][3]);
        *(float4*)&sc[s][tg * 4 + t][ng * 4] = w;
      }
    }
  }
  __syncthreads();

  // top-k phase: wave w handles tokens 4w..4w+3 (exact machinery from passing kernel)
  int wv_ = tid >> 6;
  int ln = tid & 63;
  int s = ln >> 5, l = ln & 31;

  for (int tt = 0; tt < 4; ++tt) {
    int t = wv_ * 4 + tt;
    float lv[8];
    int li[8];
    {
      float4 v0 = *(const float4*)&sc[s][t][l * 8];
      float4 v1 = *(const float4*)&sc[s][t][l * 8 + 4];
      lv[0] = v0.x; lv[1] = v0.y; lv[2] = v0.z; lv[3] = v0.w;
      lv[4] = v1.x; lv[5] = v1.y; lv[6] = v1.z; lv[7] = v1.w;
#pragma unroll
      for (int m = 0; m < 8; ++m) li[m] = l * 8 + m;
    }
    CE(0, 1); CE(2, 3); CE(0, 2); CE(1, 3); CE(1, 2);
    CE(4, 5); CE(6, 7); CE(4, 6); CE(5, 7); CE(5, 6);
    CE(0, 4); CE(1, 5); CE(2, 6); CE(3, 7);
    CE(2, 4); CE(3, 5);
    CE(1, 2); CE(3, 4); CE(5, 6);

    float wv_cap = 0.f;
    int wn_cap = 0;
#pragma unroll
    for (int k = 0; k < 8; ++k) {
      float v = lv[0];
      int n = li[0];
#pragma unroll
      for (int off = 16; off; off >>= 1) {
        float ov = __shfl_xor(v, off);
        int on = __shfl_xor(n, off);
        if (ov > v || (ov == v && on < n)) { v = ov; n = on; }
      }
      if (l == k) { wv_cap = v; wn_cap = n; }
      if (li[0] == n) {
#pragma unroll
        for (int m = 0; m < 7; ++m) { lv[m] = lv[m + 1]; li[m] = li[m + 1]; }
        lv[7] = -INFINITY;
        li[7] = 1 << 30;
      }
    }

    int i = ln >> 3, j = ln & 7;
    float v_i = __shfl(wv_cap, i);
    float v_j = __shfl(wv_cap, 32 + j);
    int n_i = __shfl(wn_cap, i);
    int n_j = __shfl(wn_cap, 32 + j);
    float cv = v_i + v_j;
    int ci = n_i * NKEYS + n_j;
    int p = ln;
#pragma unroll
    for (int k = 2; k <= 64; k <<= 1) {
#pragma unroll
      for (int j2 = k >> 1; j2 > 0; j2 >>= 1) {
        float ov = __shfl_xor(cv, j2);
        int op = __shfl_xor(p, j2);
        bool descBlock = ((ln & k) == 0);
        bool lower = ((ln & j2) == 0);
        bool mineBefore = (cv > ov) || (cv == ov && p < op);
        bool keep = (descBlock == lower) ? mineBefore : !mineBefore;
        if (!keep) { cv = ov; p = op; }
      }
    }
    float m0 = __shfl(cv, 0);
    float e = expf(cv - m0);
    float d = e;
#pragma unroll
    for (int off = 1; off < 8; off <<= 1) d += __shfl_xor(d, off);
    int wci = __shfl(ci, p);
    if (ln < TOPK) {
      size_t o = ((size_t)(b0 + t) * NH + h) * TOPK + ln;
      wval[o] = e / d;
      widx[o] = wci;
    }
  }
}

// ---------------- Kernel C1: vals = relu(x . w_down[idx]) * wt ----------------
// One wave per 4 pairs: 4 independent 2KB row loads in flight per wave.
__global__ __launch_bounds__(256) void compute_vals(const float* __restrict__ x,
                                                    const float* __restrict__ w_down,
                                                    const int* __restrict__ widx,
                                                    const float* __restrict__ wval,
                                                    float* __restrict__ vals) {
  int tid = threadIdx.x;
  int ln = tid & 63;
  int gw = blockIdx.x * 4 + (tid >> 6);
  int b = gw >> 4;
  int pbase = b * 64 + (gw & 15) * 4;

  const float4* xr = (const float4*)(x + (size_t)b * D_MODEL);
  float4 x0 = xr[ln * 2], x1 = xr[ln * 2 + 1];

  int idx0 = widx[pbase + 0];
  int idx1 = widx[pbase + 1];
  int idx2 = widx[pbase + 2];
  int idx3 = widx[pbase + 3];
  const float4* r0 = (const float4*)(w_down + (size_t)idx0 * D_MODEL);
  const float4* r1 = (const float4*)(w_down + (size_t)idx1 * D_MODEL);
  const float4* r2 = (const float4*)(w_down + (size_t)idx2 * D_MODEL);
  const float4* r3 = (const float4*)(w_down + (size_t)idx3 * D_MODEL);
  float4 a0 = r0[ln * 2], b0 = r0[ln * 2 + 1];
  float4 a1 = r1[ln * 2], b1 = r1[ln * 2 + 1];
  float4 a2 = r2[ln * 2], b2 = r2[ln * 2 + 1];
  float4 a3 = r3[ln * 2], b3 = r3[ln * 2 + 1];

  float d0 = x0.x * a0.x + x0.y * a0.y + x0.z * a0.z + x0.w * a0.w +
             x1.x * b0.x + x1.y * b0.y + x1.z * b0.z + x1.w * b0.w;
  float d1 = x0.x * a1.x + x0.y * a1.y + x0.z * a1.z + x0.w * a1.w +
             x1.x * b1.x + x1.y * b1.y + x1.z * b1.z + x1.w * b1.w;
  float d2 = x0.x * a2.x + x0.y * a2.y + x0.z * a2.z + x0.w * a2.w +
             x1.x * b2.x + x1.y * b2.y + x1.z * b2.z + x1.w * b2.w;
  float d3 = x0.x * a3.x + x0.y * a3.y + x0.z * a3.z + x0.w * a3.w +
             x1.x * b3.x + x1.y * b3.y + x1.z * b3.z + x1.w * b3.w;

#pragma unroll
  for (int off = 32; off; off >>= 1) {
    d0 += __shfl_xor(d0, off);
    d1 += __shfl_xor(d1, off);
    d2 += __shfl_xor(d2, off);
    d3 += __shfl_xor(d3, off);
  }
  if (ln == 0) {
    vals[pbase + 0] = fmaxf(d0, 0.f) * wval[pbase + 0];
    vals[pbase + 1] = fmaxf(d1, 0.f) * wval[pbase + 1];
    vals[pbase + 2] = fmaxf(d2, 0.f) * wval[pbase + 2];
    vals[pbase + 3] = fmaxf(d3, 0.f) * wval[pbase + 3];
  }
}

// ---------------- Kernel C2: out[b] = sum_p val[p] * w_up[idx[p]] ----------------
// Round-3 measured-best form: branch skip of relu-killed pairs (~50% traffic cut).
__global__ __launch_bounds__(256) void accum_out(const float* __restrict__ w_up,
                                                 const int* __restrict__ widx,
                                                 const float* __restrict__ vals,
                                                 float* __restrict__ out) {
  int b = blockIdx.x;
  int tid = threadIdx.x;
  int ln = tid & 63, w = tid >> 6;
  __shared__ float lds_o[4][D_MODEL];

  float oa[8];
#pragma unroll
  for (int e = 0; e < 8; ++e) oa[e] = 0.f;

  for (int pp = 0; pp < 16; ++pp) {
    int pair = b * 64 + w * 16 + pp;
    float val = vals[pair];
    if (val > 0.f) {
      int idx = widx[pair];
      const float4* wu = (const float4*)(w_up + (size_t)idx * D_MODEL);
      float4 u0 = wu[ln * 2], u1 = wu[ln * 2 + 1];
      oa[0] += val * u0.x; oa[1] += val * u0.y; oa[2] += val * u0.z; oa[3] += val * u0.w;
      oa[4] += val * u1.x; oa[5] += val * u1.y; oa[6] += val * u1.z; oa[7] += val * u1.w;
    }
  }
  *(float4*)&lds_o[w][ln * 8]     = make_float4(oa[0], oa[1], oa[2], oa[3]);
  *(float4*)&lds_o[w][ln * 8 + 4] = make_float4(oa[4], oa[5], oa[6], oa[7]);
  __syncthreads();
  for (int d = tid; d < D_MODEL; d += 256) {
    out[(size_t)b * D_MODEL + d] = lds_o[0][d] + lds_o[1][d] + lds_o[2][d] + lds_o[3][d];
  }
}

extern "C" void kernel_launch(void* const* d_in, const int* in_sizes, int n_in,
                              void* d_out, int out_size, void* d_ws, size_t ws_size,
                              hipStream_t stream) {
  const float* queries = (const float*)d_in[0];
  const float* Wq      = (const float*)d_in[1];
  const float* bq      = (const float*)d_in[2];
  const float* keys    = (const float*)d_in[3];
  const float* w_down  = (const float*)d_in[4];
  const float* w_up    = (const float*)d_in[5];
  float* outp = (float*)d_out;

  char* base = (char*)d_ws;
  float* qbuf = (float*)base;                                   // 8 MB
  float* vals = (float*)(base + (size_t)8 * 1024 * 1024);       // 512 KB
  int*   widx = (int*)(base + (size_t)9 * 1024 * 1024);         // 512 KB
  float* wval = (float*)(base + (size_t)10 * 1024 * 1024);      // 512 KB

  qproj_gemm<<<dim3(16, 32), 256, 0, stream>>>(queries, Wq, bq, qbuf);
  score_topk_fused<<<dim3(128, 8), 256, 0, stream>>>(qbuf, keys, widx, wval);
  compute_vals<<<8192, 256, 0, stream>>>(queries, w_down, widx, wval, vals);
  accum_out<<<2048, 256, 0, stream>>>(w_up, widx, vals, outp);
}

// Round 7
// 150.189 us; speedup vs baseline: 1.3252x; 1.3252x over previous
//
#include <hip/hip_runtime.h>
#include <math.h>

#define D_MODEL 512
#define NH      8
#define DK      128
#define HALFD   64
#define NKEYS   256
#define TOPK    8
#define NTOK    2048

// ---------------- Kernel A: q = x @ Wq + bq  (fp32 tiled GEMM) ----------------
// M=2048, N=1024, K=512. BM=BN=64, BK=16, 256 threads, 4x4/thread, 512 blocks = 2/CU.
// Register prefetch: next tile's global loads issue right after the barrier and
// overlap the 16-step FMA block (previously latency was exposed between barriers).
__global__ __launch_bounds__(256) void qproj_gemm(const float* __restrict__ A,
                                                  const float* __restrict__ B,
                                                  const float* __restrict__ bias,
                                                  float* __restrict__ C) {
  const int N = NH * DK, K = D_MODEL;
  __shared__ float As[16][68];
  __shared__ float Bs[16][68];
  int tid = threadIdx.x;
  int tx = tid & 15, ty = tid >> 4;
  int m0 = blockIdx.y * 64, n0 = blockIdx.x * 64;
  int arow = tid >> 2, akk = (tid & 3) << 2;
  int bkr = tid >> 4, bnn = (tid & 15) << 2;
  const float* Aptr = A + (size_t)(m0 + arow) * K + akk;
  const float* Bptr = B + (size_t)bkr * N + n0 + bnn;

  float4 aReg = *(const float4*)Aptr;
  float4 bReg = *(const float4*)Bptr;

  float c[4][4];
#pragma unroll
  for (int i = 0; i < 4; ++i)
#pragma unroll
    for (int j = 0; j < 4; ++j) c[i][j] = 0.f;

  for (int k0 = 0; k0 < K; k0 += 16) {
    // commit staged regs to LDS
    As[akk + 0][arow] = aReg.x;
    As[akk + 1][arow] = aReg.y;
    As[akk + 2][arow] = aReg.z;
    As[akk + 3][arow] = aReg.w;
    *(float4*)&Bs[bkr][bnn] = bReg;
    __syncthreads();
    // prefetch next tile (overlaps with compute below)
    if (k0 + 16 < K) {
      aReg = *(const float4*)(Aptr + k0 + 16);
      bReg = *(const float4*)(Bptr + (size_t)(k0 + 16) * N);
    }
#pragma unroll
    for (int k = 0; k < 16; ++k) {
      float4 a = *(const float4*)&As[k][ty << 2];
      float4 b = *(const float4*)&Bs[k][tx << 2];
      float av[4] = {a.x, a.y, a.z, a.w};
      float bv[4] = {b.x, b.y, b.z, b.w};
#pragma unroll
      for (int i = 0; i < 4; ++i)
#pragma unroll
        for (int j = 0; j < 4; ++j) c[i][j] += av[i] * bv[j];
    }
    __syncthreads();
  }
#pragma unroll
  for (int i = 0; i < 4; ++i) {
    int m = m0 + (ty << 2) + i;
#pragma unroll
    for (int j = 0; j < 4; ++j) {
      int n = n0 + (tx << 2) + j;
      C[(size_t)m * N + n] = c[i][j] + bias[n];
    }
  }
}

// ---------------- Kernel A2: scores = q_half @ keys^T ----------------
__global__ __launch_bounds__(256) void score_gemm(const float* __restrict__ qbuf,
                                                  const float* __restrict__ keys,
                                                  float* __restrict__ scores) {
  __shared__ float As[16][68];
  __shared__ float Bs[16][68];
  int tid = threadIdx.x;
  int tx = tid & 15, ty = tid >> 4;
  int n0 = blockIdx.x * 64, m0 = blockIdx.y * 64, slab = blockIdx.z;
  const float* Ap = qbuf + (size_t)slab * HALFD;
  const float* Bp = keys + (size_t)slab * NKEYS * HALFD;
  float c[4][4];
#pragma unroll
  for (int i = 0; i < 4; ++i)
#pragma unroll
    for (int j = 0; j < 4; ++j) c[i][j] = 0.f;

  for (int k0 = 0; k0 < HALFD; k0 += 16) {
    int row = tid >> 2, kk = (tid & 3) << 2;
    {
      float4 av = *(const float4*)(Ap + (size_t)(m0 + row) * (NH * DK) + k0 + kk);
      As[kk + 0][row] = av.x;
      As[kk + 1][row] = av.y;
      As[kk + 2][row] = av.z;
      As[kk + 3][row] = av.w;
    }
    {
      float4 bv = *(const float4*)(Bp + (size_t)(n0 + row) * HALFD + k0 + kk);
      Bs[kk + 0][row] = bv.x;
      Bs[kk + 1][row] = bv.y;
      Bs[kk + 2][row] = bv.z;
      Bs[kk + 3][row] = bv.w;
    }
    __syncthreads();
#pragma unroll
    for (int k = 0; k < 16; ++k) {
      float4 a = *(const float4*)&As[k][ty << 2];
      float4 b = *(const float4*)&Bs[k][tx << 2];
      float av[4] = {a.x, a.y, a.z, a.w};
      float bv[4] = {b.x, b.y, b.z, b.w};
#pragma unroll
      for (int i = 0; i < 4; ++i)
#pragma unroll
        for (int j = 0; j < 4; ++j) c[i][j] += av[i] * bv[j];
    }
    __syncthreads();
  }
#pragma unroll
  for (int i = 0; i < 4; ++i) {
    int m = m0 + (ty << 2) + i;
    float4 cv = make_float4(c[i][0], c[i][1], c[i][2], c[i][3]);
    *(float4*)&scores[((size_t)m * 16 + slab) * NKEYS + n0 + (tx << 2)] = cv;
  }
}

// ---------------- Kernel B: two-stage top-k + softmax ----------------
#define CE(a, b)                                                        \
  do {                                                                  \
    if (lv[a] < lv[b] || (lv[a] == lv[b] && li[a] > li[b])) {           \
      float tv_ = lv[a]; lv[a] = lv[b]; lv[b] = tv_;                    \
      int ti_ = li[a]; li[a] = li[b]; li[b] = ti_;                      \
    }                                                                   \
  } while (0)

__global__ __launch_bounds__(256) void topk_kernel(const float* __restrict__ scores,
                                                   int* __restrict__ widx,
                                                   float* __restrict__ wval) {
  int tid = threadIdx.x;
  int task = blockIdx.x * 4 + (tid >> 6);
  int ln = tid & 63;
  int b = task >> 3, h = task & 7;
  int s = ln >> 5, l = ln & 31;

  const float* sp = scores + ((size_t)b * 16 + h * 2 + s) * NKEYS + l * 8;
  float lv[8];
  int li[8];
  {
    float4 v0 = *(const float4*)sp;
    float4 v1 = *(const float4*)(sp + 4);
    lv[0] = v0.x; lv[1] = v0.y; lv[2] = v0.z; lv[3] = v0.w;
    lv[4] = v1.x; lv[5] = v1.y; lv[6] = v1.z; lv[7] = v1.w;
#pragma unroll
    for (int m = 0; m < 8; ++m) li[m] = l * 8 + m;
  }
  CE(0, 1); CE(2, 3); CE(0, 2); CE(1, 3); CE(1, 2);
  CE(4, 5); CE(6, 7); CE(4, 6); CE(5, 7); CE(5, 6);
  CE(0, 4); CE(1, 5); CE(2, 6); CE(3, 7);
  CE(2, 4); CE(3, 5);
  CE(1, 2); CE(3, 4); CE(5, 6);

  float wv_cap = 0.f;
  int wn_cap = 0;
#pragma unroll
  for (int k = 0; k < 8; ++k) {
    float v = lv[0];
    int n = li[0];
#pragma unroll
    for (int off = 16; off; off >>= 1) {
      float ov = __shfl_xor(v, off);
      int on = __shfl_xor(n, off);
      if (ov > v || (ov == v && on < n)) { v = ov; n = on; }
    }
    if (l == k) { wv_cap = v; wn_cap = n; }
    if (li[0] == n) {
#pragma unroll
      for (int m = 0; m < 7; ++m) { lv[m] = lv[m + 1]; li[m] = li[m + 1]; }
      lv[7] = -INFINITY;
      li[7] = 1 << 30;
    }
  }

  int i = ln >> 3, j = ln & 7;
  float v_i = __shfl(wv_cap, i);
  float v_j = __shfl(wv_cap, 32 + j);
  int n_i = __shfl(wn_cap, i);
  int n_j = __shfl(wn_cap, 32 + j);
  float cv = v_i + v_j;
  int ci = n_i * NKEYS + n_j;
  int p = ln;
#pragma unroll
  for (int k = 2; k <= 64; k <<= 1) {
#pragma unroll
    for (int j2 = k >> 1; j2 > 0; j2 >>= 1) {
      float ov = __shfl_xor(cv, j2);
      int op = __shfl_xor(p, j2);
      bool descBlock = ((ln & k) == 0);
      bool lower = ((ln & j2) == 0);
      bool mineBefore = (cv > ov) || (cv == ov && p < op);
      bool keep = (descBlock == lower) ? mineBefore : !mineBefore;
      if (!keep) { cv = ov; p = op; }
    }
  }
  float m0 = __shfl(cv, 0);
  float e = expf(cv - m0);
  float d = e;
#pragma unroll
  for (int off = 1; off < 8; off <<= 1) d += __shfl_xor(d, off);
  int wci = __shfl(ci, p);
  if (ln < TOPK) {
    size_t o = ((size_t)b * NH + h) * TOPK + ln;
    wval[o] = e / d;
    widx[o] = wci;
  }
}

// ---------------- Kernel C1: vals = relu(x . w_down[idx]) * wt ----------------
// One wave per 4 pairs: 4 independent 2KB row loads in flight per wave (round-3 form).
__global__ __launch_bounds__(256) void compute_vals(const float* __restrict__ x,
                                                    const float* __restrict__ w_down,
                                                    const int* __restrict__ widx,
                                                    const float* __restrict__ wval,
                                                    float* __restrict__ vals) {
  int tid = threadIdx.x;
  int ln = tid & 63;
  int gw = blockIdx.x * 4 + (tid >> 6);
  int b = gw >> 4;
  int pbase = b * 64 + (gw & 15) * 4;

  const float4* xr = (const float4*)(x + (size_t)b * D_MODEL);
  float4 x0 = xr[ln * 2], x1 = xr[ln * 2 + 1];

  int idx0 = widx[pbase + 0];
  int idx1 = widx[pbase + 1];
  int idx2 = widx[pbase + 2];
  int idx3 = widx[pbase + 3];
  const float4* r0 = (const float4*)(w_down + (size_t)idx0 * D_MODEL);
  const float4* r1 = (const float4*)(w_down + (size_t)idx1 * D_MODEL);
  const float4* r2 = (const float4*)(w_down + (size_t)idx2 * D_MODEL);
  const float4* r3 = (const float4*)(w_down + (size_t)idx3 * D_MODEL);
  float4 a0 = r0[ln * 2], b0 = r0[ln * 2 + 1];
  float4 a1 = r1[ln * 2], b1 = r1[ln * 2 + 1];
  float4 a2 = r2[ln * 2], b2 = r2[ln * 2 + 1];
  float4 a3 = r3[ln * 2], b3 = r3[ln * 2 + 1];

  float d0 = x0.x * a0.x + x0.y * a0.y + x0.z * a0.z + x0.w * a0.w +
             x1.x * b0.x + x1.y * b0.y + x1.z * b0.z + x1.w * b0.w;
  float d1 = x0.x * a1.x + x0.y * a1.y + x0.z * a1.z + x0.w * a1.w +
             x1.x * b1.x + x1.y * b1.y + x1.z * b1.z + x1.w * b1.w;
  float d2 = x0.x * a2.x + x0.y * a2.y + x0.z * a2.z + x0.w * a2.w +
             x1.x * b2.x + x1.y * b2.y + x1.z * b2.z + x1.w * b2.w;
  float d3 = x0.x * a3.x + x0.y * a3.y + x0.z * a3.z + x0.w * a3.w +
             x1.x * b3.x + x1.y * b3.y + x1.z * b3.z + x1.w * b3.w;

#pragma unroll
  for (int off = 32; off; off >>= 1) {
    d0 += __shfl_xor(d0, off);
    d1 += __shfl_xor(d1, off);
    d2 += __shfl_xor(d2, off);
    d3 += __shfl_xor(d3, off);
  }
  if (ln == 0) {
    vals[pbase + 0] = fmaxf(d0, 0.f) * wval[pbase + 0];
    vals[pbase + 1] = fmaxf(d1, 0.f) * wval[pbase + 1];
    vals[pbase + 2] = fmaxf(d2, 0.f) * wval[pbase + 2];
    vals[pbase + 3] = fmaxf(d3, 0.f) * wval[pbase + 3];
  }
}

// ---------------- Kernel C2: out[b] = sum_p val[p] * w_up[idx[p]] ----------------
// Branch form (measured best) at 512 threads: 8 waves x 8 pairs — halves the
// per-wave serial load->branch chain vs 4x16.
__global__ __launch_bounds__(512) void accum_out(const float* __restrict__ w_up,
                                                 const int* __restrict__ widx,
                                                 const float* __restrict__ vals,
                                                 float* __restrict__ out) {
  int b = blockIdx.x;
  int tid = threadIdx.x;
  int ln = tid & 63, w = tid >> 6;
  __shared__ float lds_o[8][D_MODEL];

  float oa[8];
#pragma unroll
  for (int e = 0; e < 8; ++e) oa[e] = 0.f;

  for (int pp = 0; pp < 8; ++pp) {
    int pair = b * 64 + w * 8 + pp;
    float val = vals[pair];
    if (val > 0.f) {
      int idx = widx[pair];
      const float4* wu = (const float4*)(w_up + (size_t)idx * D_MODEL);
      float4 u0 = wu[ln * 2], u1 = wu[ln * 2 + 1];
      oa[0] += val * u0.x; oa[1] += val * u0.y; oa[2] += val * u0.z; oa[3] += val * u0.w;
      oa[4] += val * u1.x; oa[5] += val * u1.y; oa[6] += val * u1.z; oa[7] += val * u1.w;
    }
  }
  *(float4*)&lds_o[w][ln * 8]     = make_float4(oa[0], oa[1], oa[2], oa[3]);
  *(float4*)&lds_o[w][ln * 8 + 4] = make_float4(oa[4], oa[5], oa[6], oa[7]);
  __syncthreads();
  {
    int d = tid;  // 512 threads, D_MODEL=512: one element each
    float acc = lds_o[0][d] + lds_o[1][d] + lds_o[2][d] + lds_o[3][d] +
                lds_o[4][d] + lds_o[5][d] + lds_o[6][d] + lds_o[7][d];
    out[(size_t)b * D_MODEL + d] = acc;
  }
}

extern "C" void kernel_launch(void* const* d_in, const int* in_sizes, int n_in,
                              void* d_out, int out_size, void* d_ws, size_t ws_size,
                              hipStream_t stream) {
  const float* queries = (const float*)d_in[0];
  const float* Wq      = (const float*)d_in[1];
  const float* bq      = (const float*)d_in[2];
  const float* keys    = (const float*)d_in[3];
  const float* w_down  = (const float*)d_in[4];
  const float* w_up    = (const float*)d_in[5];
  float* outp = (float*)d_out;

  char* base = (char*)d_ws;
  float* qbuf   = (float*)base;                                    // 8 MB (dead after score_gemm)
  float* scores = (float*)(base + (size_t)8 * 1024 * 1024);        // 33.5 MB
  int*   widx   = (int*)(base + (size_t)42 * 1024 * 1024);         // 512 KB
  float* wval   = (float*)(base + (size_t)43 * 1024 * 1024);       // 512 KB
  float* vals   = (float*)base;                                    // 512 KB, overlays dead qbuf

  qproj_gemm<<<dim3(16, 32), 256, 0, stream>>>(queries, Wq, bq, qbuf);
  score_gemm<<<dim3(4, 32, 16), 256, 0, stream>>>(qbuf, keys, scores);
  topk_kernel<<<4096, 256, 0, stream>>>(scores, widx, wval);
  compute_vals<<<8192, 256, 0, stream>>>(queries, w_down, widx, wval, vals);
  accum_out<<<2048, 512, 0, stream>>>(w_up, widx, vals, outp);
}

// Round 8
// 146.927 us; speedup vs baseline: 1.3546x; 1.0222x over previous
//
#include <hip/hip_runtime.h>
#include <math.h>

#define D_MODEL 512
#define NH      8
#define DK      128
#define HALFD   64
#define NKEYS   256
#define TOPK    8
#define NTOK    2048

// ---------------- Kernel A: q = x @ Wq + bq  (fp32 tiled GEMM) ----------------
// M=2048, N=1024, K=512. BM=BN=64, BK=16, 256 threads, 4x4/thread, 512 blocks = 2/CU.
__global__ __launch_bounds__(256) void qproj_gemm(const float* __restrict__ A,
                                                  const float* __restrict__ B,
                                                  const float* __restrict__ bias,
                                                  float* __restrict__ C) {
  const int N = NH * DK, K = D_MODEL;
  __shared__ float As[16][68];
  __shared__ float Bs[16][68];
  int tid = threadIdx.x;
  int tx = tid & 15, ty = tid >> 4;
  int m0 = blockIdx.y * 64, n0 = blockIdx.x * 64;
  int arow = tid >> 2, akk = (tid & 3) << 2;
  int bkr = tid >> 4, bnn = (tid & 15) << 2;
  const float* Aptr = A + (size_t)(m0 + arow) * K + akk;
  const float* Bptr = B + (size_t)bkr * N + n0 + bnn;

  float4 aReg = *(const float4*)Aptr;
  float4 bReg = *(const float4*)Bptr;

  float c[4][4];
#pragma unroll
  for (int i = 0; i < 4; ++i)
#pragma unroll
    for (int j = 0; j < 4; ++j) c[i][j] = 0.f;

  for (int k0 = 0; k0 < K; k0 += 16) {
    As[akk + 0][arow] = aReg.x;
    As[akk + 1][arow] = aReg.y;
    As[akk + 2][arow] = aReg.z;
    As[akk + 3][arow] = aReg.w;
    *(float4*)&Bs[bkr][bnn] = bReg;
    __syncthreads();
    if (k0 + 16 < K) {
      aReg = *(const float4*)(Aptr + k0 + 16);
      bReg = *(const float4*)(Bptr + (size_t)(k0 + 16) * N);
    }
#pragma unroll
    for (int k = 0; k < 16; ++k) {
      float4 a = *(const float4*)&As[k][ty << 2];
      float4 b = *(const float4*)&Bs[k][tx << 2];
      float av[4] = {a.x, a.y, a.z, a.w};
      float bv[4] = {b.x, b.y, b.z, b.w};
#pragma unroll
      for (int i = 0; i < 4; ++i)
#pragma unroll
        for (int j = 0; j < 4; ++j) c[i][j] += av[i] * bv[j];
    }
    __syncthreads();
  }
#pragma unroll
  for (int i = 0; i < 4; ++i) {
    int m = m0 + (ty << 2) + i;
#pragma unroll
    for (int j = 0; j < 4; ++j) {
      int n = n0 + (tx << 2) + j;
      C[(size_t)m * N + n] = c[i][j] + bias[n];
    }
  }
}

// ---------------- Kernel A2: scores = q_half @ keys^T ----------------
__global__ __launch_bounds__(256) void score_gemm(const float* __restrict__ qbuf,
                                                  const float* __restrict__ keys,
                                                  float* __restrict__ scores) {
  __shared__ float As[16][68];
  __shared__ float Bs[16][68];
  int tid = threadIdx.x;
  int tx = tid & 15, ty = tid >> 4;
  int n0 = blockIdx.x * 64, m0 = blockIdx.y * 64, slab = blockIdx.z;
  const float* Ap = qbuf + (size_t)slab * HALFD;
  const float* Bp = keys + (size_t)slab * NKEYS * HALFD;
  float c[4][4];
#pragma unroll
  for (int i = 0; i < 4; ++i)
#pragma unroll
    for (int j = 0; j < 4; ++j) c[i][j] = 0.f;

  for (int k0 = 0; k0 < HALFD; k0 += 16) {
    int row = tid >> 2, kk = (tid & 3) << 2;
    {
      float4 av = *(const float4*)(Ap + (size_t)(m0 + row) * (NH * DK) + k0 + kk);
      As[kk + 0][row] = av.x;
      As[kk + 1][row] = av.y;
      As[kk + 2][row] = av.z;
      As[kk + 3][row] = av.w;
    }
    {
      float4 bv = *(const float4*)(Bp + (size_t)(n0 + row) * HALFD + k0 + kk);
      Bs[kk + 0][row] = bv.x;
      Bs[kk + 1][row] = bv.y;
      Bs[kk + 2][row] = bv.z;
      Bs[kk + 3][row] = bv.w;
    }
    __syncthreads();
#pragma unroll
    for (int k = 0; k < 16; ++k) {
      float4 a = *(const float4*)&As[k][ty << 2];
      float4 b = *(const float4*)&Bs[k][tx << 2];
      float av[4] = {a.x, a.y, a.z, a.w};
      float bv[4] = {b.x, b.y, b.z, b.w};
#pragma unroll
      for (int i = 0; i < 4; ++i)
#pragma unroll
        for (int j = 0; j < 4; ++j) c[i][j] += av[i] * bv[j];
    }
    __syncthreads();
  }
#pragma unroll
  for (int i = 0; i < 4; ++i) {
    int m = m0 + (ty << 2) + i;
    float4 cv = make_float4(c[i][0], c[i][1], c[i][2], c[i][3]);
    *(float4*)&scores[((size_t)m * 16 + slab) * NKEYS + n0 + (tx << 2)] = cv;
  }
}

// ---------------- Kernel B: two-stage top-k + softmax ----------------
#define CE(a, b)                                                        \
  do {                                                                  \
    if (lv[a] < lv[b] || (lv[a] == lv[b] && li[a] > li[b])) {           \
      float tv_ = lv[a]; lv[a] = lv[b]; lv[b] = tv_;                    \
      int ti_ = li[a]; li[a] = li[b]; li[b] = ti_;                      \
    }                                                                   \
  } while (0)

__global__ __launch_bounds__(256) void topk_kernel(const float* __restrict__ scores,
                                                   int* __restrict__ widx,
                                                   float* __restrict__ wval) {
  int tid = threadIdx.x;
  int task = blockIdx.x * 4 + (tid >> 6);
  int ln = tid & 63;
  int b = task >> 3, h = task & 7;
  int s = ln >> 5, l = ln & 31;

  const float* sp = scores + ((size_t)b * 16 + h * 2 + s) * NKEYS + l * 8;
  float lv[8];
  int li[8];
  {
    float4 v0 = *(const float4*)sp;
    float4 v1 = *(const float4*)(sp + 4);
    lv[0] = v0.x; lv[1] = v0.y; lv[2] = v0.z; lv[3] = v0.w;
    lv[4] = v1.x; lv[5] = v1.y; lv[6] = v1.z; lv[7] = v1.w;
#pragma unroll
    for (int m = 0; m < 8; ++m) li[m] = l * 8 + m;
  }
  CE(0, 1); CE(2, 3); CE(0, 2); CE(1, 3); CE(1, 2);
  CE(4, 5); CE(6, 7); CE(4, 6); CE(5, 7); CE(5, 6);
  CE(0, 4); CE(1, 5); CE(2, 6); CE(3, 7);
  CE(2, 4); CE(3, 5);
  CE(1, 2); CE(3, 4); CE(5, 6);

  float wv_cap = 0.f;
  int wn_cap = 0;
#pragma unroll
  for (int k = 0; k < 8; ++k) {
    float v = lv[0];
    int n = li[0];
#pragma unroll
    for (int off = 16; off; off >>= 1) {
      float ov = __shfl_xor(v, off);
      int on = __shfl_xor(n, off);
      if (ov > v || (ov == v && on < n)) { v = ov; n = on; }
    }
    if (l == k) { wv_cap = v; wn_cap = n; }
    if (li[0] == n) {
#pragma unroll
      for (int m = 0; m < 7; ++m) { lv[m] = lv[m + 1]; li[m] = li[m + 1]; }
      lv[7] = -INFINITY;
      li[7] = 1 << 30;
    }
  }

  int i = ln >> 3, j = ln & 7;
  float v_i = __shfl(wv_cap, i);
  float v_j = __shfl(wv_cap, 32 + j);
  int n_i = __shfl(wn_cap, i);
  int n_j = __shfl(wn_cap, 32 + j);
  float cv = v_i + v_j;
  int ci = n_i * NKEYS + n_j;
  int p = ln;
#pragma unroll
  for (int k = 2; k <= 64; k <<= 1) {
#pragma unroll
    for (int j2 = k >> 1; j2 > 0; j2 >>= 1) {
      float ov = __shfl_xor(cv, j2);
      int op = __shfl_xor(p, j2);
      bool descBlock = ((ln & k) == 0);
      bool lower = ((ln & j2) == 0);
      bool mineBefore = (cv > ov) || (cv == ov && p < op);
      bool keep = (descBlock == lower) ? mineBefore : !mineBefore;
      if (!keep) { cv = ov; p = op; }
    }
  }
  float m0 = __shfl(cv, 0);
  float e = expf(cv - m0);
  float d = e;
#pragma unroll
  for (int off = 1; off < 8; off <<= 1) d += __shfl_xor(d, off);
  int wci = __shfl(ci, p);
  if (ln < TOPK) {
    size_t o = ((size_t)b * NH + h) * TOPK + ln;
    wval[o] = e / d;
    widx[o] = wci;
  }
}

// ---------------- Kernel C: fused gather (down-dot + relu*wt + up-accum) ----------------
// One block (1024 thr = 16 waves) per token; wave w owns pairs w*4..w*4+3.
// Phase 1: 4 independent w_down row loads -> dots -> full xor-reduce (sum lands in
// EVERY lane, so no barrier / LDS handoff needed). Phase 2: branch-skip w_up loads
// (val>0 only, ~50% traffic cut), oa accumulate. One barrier, 16-partial LDS reduce.
__global__ __launch_bounds__(1024) void gather_fused(const float* __restrict__ x,
                                                     const float* __restrict__ w_down,
                                                     const float* __restrict__ w_up,
                                                     const int* __restrict__ widx,
                                                     const float* __restrict__ wval,
                                                     float* __restrict__ out) {
  int b = blockIdx.x;
  int tid = threadIdx.x;
  int ln = tid & 63, w = tid >> 6;  // w: 0..15
  __shared__ float part[16][D_MODEL];  // 32 KB

  int pbase = b * 64 + w * 4;
  const float4* xr = (const float4*)(x + (size_t)b * D_MODEL);
  float4 x0 = xr[ln * 2], x1 = xr[ln * 2 + 1];

  // ---- phase 1: down dots (4 independent 2KB rows in flight) ----
  int idx0 = widx[pbase + 0];
  int idx1 = widx[pbase + 1];
  int idx2 = widx[pbase + 2];
  int idx3 = widx[pbase + 3];
  const float4* r0 = (const float4*)(w_down + (size_t)idx0 * D_MODEL);
  const float4* r1 = (const float4*)(w_down + (size_t)idx1 * D_MODEL);
  const float4* r2 = (const float4*)(w_down + (size_t)idx2 * D_MODEL);
  const float4* r3 = (const float4*)(w_down + (size_t)idx3 * D_MODEL);
  float4 a0 = r0[ln * 2], b0 = r0[ln * 2 + 1];
  float4 a1 = r1[ln * 2], b1 = r1[ln * 2 + 1];
  float4 a2 = r2[ln * 2], b2 = r2[ln * 2 + 1];
  float4 a3 = r3[ln * 2], b3 = r3[ln * 2 + 1];

  float d0 = x0.x * a0.x + x0.y * a0.y + x0.z * a0.z + x0.w * a0.w +
             x1.x * b0.x + x1.y * b0.y + x1.z * b0.z + x1.w * b0.w;
  float d1 = x0.x * a1.x + x0.y * a1.y + x0.z * a1.z + x0.w * a1.w +
             x1.x * b1.x + x1.y * b1.y + x1.z * b1.z + x1.w * b1.w;
  float d2 = x0.x * a2.x + x0.y * a2.y + x0.z * a2.z + x0.w * a2.w +
             x1.x * b2.x + x1.y * b2.y + x1.z * b2.z + x1.w * b2.w;
  float d3 = x0.x * a3.x + x0.y * a3.y + x0.z * a3.z + x0.w * a3.w +
             x1.x * b3.x + x1.y * b3.y + x1.z * b3.z + x1.w * b3.w;

#pragma unroll
  for (int off = 32; off; off >>= 1) {
    d0 += __shfl_xor(d0, off);
    d1 += __shfl_xor(d1, off);
    d2 += __shfl_xor(d2, off);
    d3 += __shfl_xor(d3, off);
  }
  float val0 = fmaxf(d0, 0.f) * wval[pbase + 0];
  float val1 = fmaxf(d1, 0.f) * wval[pbase + 1];
  float val2 = fmaxf(d2, 0.f) * wval[pbase + 2];
  float val3 = fmaxf(d3, 0.f) * wval[pbase + 3];

  // ---- phase 2: up accumulate (branch-skip dead pairs) ----
  float oa[8];
#pragma unroll
  for (int e = 0; e < 8; ++e) oa[e] = 0.f;

  float vv[4] = {val0, val1, val2, val3};
  int ii[4] = {idx0, idx1, idx2, idx3};
#pragma unroll
  for (int r = 0; r < 4; ++r) {
    float val = vv[r];
    if (val > 0.f) {
      const float4* wu = (const float4*)(w_up + (size_t)ii[r] * D_MODEL);
      float4 u0 = wu[ln * 2], u1 = wu[ln * 2 + 1];
      oa[0] += val * u0.x; oa[1] += val * u0.y; oa[2] += val * u0.z; oa[3] += val * u0.w;
      oa[4] += val * u1.x; oa[5] += val * u1.y; oa[6] += val * u1.z; oa[7] += val * u1.w;
    }
  }
  *(float4*)&part[w][ln * 8]     = make_float4(oa[0], oa[1], oa[2], oa[3]);
  *(float4*)&part[w][ln * 8 + 4] = make_float4(oa[4], oa[5], oa[6], oa[7]);
  __syncthreads();
  if (tid < D_MODEL) {
    float acc = 0.f;
#pragma unroll
    for (int ww = 0; ww < 16; ++ww) acc += part[ww][tid];
    out[(size_t)b * D_MODEL + tid] = acc;
  }
}

extern "C" void kernel_launch(void* const* d_in, const int* in_sizes, int n_in,
                              void* d_out, int out_size, void* d_ws, size_t ws_size,
                              hipStream_t stream) {
  const float* queries = (const float*)d_in[0];
  const float* Wq      = (const float*)d_in[1];
  const float* bq      = (const float*)d_in[2];
  const float* keys    = (const float*)d_in[3];
  const float* w_down  = (const float*)d_in[4];
  const float* w_up    = (const float*)d_in[5];
  float* outp = (float*)d_out;

  char* base = (char*)d_ws;
  float* qbuf   = (float*)base;                                    // 8 MB
  float* scores = (float*)(base + (size_t)8 * 1024 * 1024);        // 33.5 MB
  int*   widx   = (int*)(base + (size_t)42 * 1024 * 1024);         // 512 KB
  float* wval   = (float*)(base + (size_t)43 * 1024 * 1024);       // 512 KB

  qproj_gemm<<<dim3(16, 32), 256, 0, stream>>>(queries, Wq, bq, qbuf);
  score_gemm<<<dim3(4, 32, 16), 256, 0, stream>>>(qbuf, keys, scores);
  topk_kernel<<<4096, 256, 0, stream>>>(scores, widx, wval);
  gather_fused<<<2048, 1024, 0, stream>>>(queries, w_down, w_up, widx, wval, outp);
}